// Round 11
// baseline (177.437 us; speedup 1.0000x reference)
//
#include <hip/hip_runtime.h>

// MultiHeadSelfAttention: B=2, N=2048, D=768, H=12, DH=64, scale=1/8.
// d_in / d_out are FP32; grading is bf16-leniency (2% of absmax).
// R11 = R10 with exp2f restored (inline-asm v_exp_f32 caused a trans-use
//     hazard the compiler can't guard inside asm -> decorrelated softmax
//     weights, absmax 0.1). Everything else identical to R10.
// R9/R10: attn waves split (q-half x key-half) -> K/V LDS fragment reads
//     2x-shared instead of 4x-duplicated (96->64 KB per block-iter).

#define CB 2
#define CN 2048
#define CD 768
#define CH 12
#define CDH 64
// exp(s/8) = exp2(s * 0.125 * log2(e)) ; folded into Q at QKV epilogue
#define CEXPSCALE 0.18033688f

typedef __bf16 bf16x8 __attribute__((ext_vector_type(8)));
typedef float f32x4 __attribute__((ext_vector_type(4)));
typedef unsigned short u16x8 __attribute__((ext_vector_type(8)));

static __device__ __forceinline__ unsigned short f2bf(float f) {
  union { float f; unsigned u; } v; v.f = f;
  unsigned r = v.u + 0x7fffu + ((v.u >> 16) & 1u);  // RNE
  return (unsigned short)(r >> 16);
}

// async global->LDS, 16B per lane; LDS dest = wave-uniform base + lane*16
static __device__ __forceinline__ void gld_lds16(const unsigned short* g, unsigned short* lds_base) {
  __builtin_amdgcn_global_load_lds(
      (const __attribute__((address_space(1))) unsigned int*)g,
      (__attribute__((address_space(3))) unsigned int*)(unsigned int)(unsigned long long)lds_base,
      16, 0, 0);
}

// ---------------- fused prep: cvt x -> bf16 AND transpose+cvt both weights ----
__global__ __launch_bounds__(256) void prep(const float* __restrict__ x,
                                            unsigned short* __restrict__ xb,
                                            const float* __restrict__ w_qkv,
                                            unsigned short* __restrict__ wqkv_t,
                                            const float* __restrict__ w_proj,
                                            unsigned short* __restrict__ wproj_t) {
  __shared__ __align__(16) unsigned short t[64][72];
  const int bid = blockIdx.x, tid = threadIdx.x;
#pragma unroll
  for (int it = 0; it < 2; ++it) {
    size_t i = ((size_t)(bid * 2 + it) * 256 + tid) * 8;
    f32x4 a = *(const f32x4*)&x[i];
    f32x4 b = *(const f32x4*)&x[i + 4];
    u16x8 o;
#pragma unroll
    for (int j = 0; j < 4; ++j) { o[j] = f2bf(a[j]); o[4 + j] = f2bf(b[j]); }
    *(u16x8*)&xb[i] = o;
  }
  if (bid >= 576) return;
  const float* src; unsigned short* dst; int R, C, c0, r0;
  if (bid < 432) { src = w_qkv; dst = wqkv_t; R = 768; C = 2304; c0 = (bid % 36) * 64; r0 = (bid / 36) * 64; }
  else { int u = bid - 432; src = w_proj; dst = wproj_t; R = 768; C = 768; c0 = (u % 12) * 64; r0 = (u / 12) * 64; }
#pragma unroll
  for (int i = 0; i < 4; ++i) {
    int c = tid + i * 256;
    int row = c >> 4, cc = (c & 15) * 4;
    f32x4 v = *(const f32x4*)&src[(size_t)(r0 + row) * C + c0 + cc];
#pragma unroll
    for (int j = 0; j < 4; ++j) t[row][cc + j] = f2bf(v[j]);
  }
  __syncthreads();
#pragma unroll
  for (int i = 0; i < 2; ++i) {
    int c = tid + i * 256;
    int drow = c >> 3, rc = (c & 7) * 8;
    u16x8 v;
#pragma unroll
    for (int j = 0; j < 8; ++j) v[j] = t[rc + j][drow];
    *(u16x8*)&dst[(size_t)(c0 + drow) * R + r0 + rc] = v;
  }
}

// ---------------- GEMM, double-buffered (R8, unchanged) ----------------------
extern __shared__ __align__(16) unsigned short smem[];

template <int TM, int TN>
__global__ __launch_bounds__(256, 4) void gemm_db(const unsigned short* __restrict__ A,
                                                  const unsigned short* __restrict__ Bt,
                                                  const float* __restrict__ bias,
                                                  int M, int N, int K, int mode,
                                                  unsigned short* __restrict__ o0,
                                                  unsigned short* __restrict__ o1,
                                                  unsigned short* __restrict__ o2,
                                                  float* __restrict__ outF) {
  constexpr int NT = TN / 32;
  unsigned short* As = smem;
  unsigned short* Bs = smem + 2 * TM * 32;
  unsigned short* Ct = smem;
  const int tid = threadIdx.x;
  const int w = tid >> 6, lane = tid & 63, quad = lane >> 4, lc = lane & 15;
  const int wm = (w >> 1) * 32, wn = (w & 1) * (TN / 2);
  const int row0 = blockIdx.y * TM, col0 = blockIdx.x * TN;
  f32x4 acc[2][NT] = {};

  const int rl = lane >> 2, cl = lane & 3;
  const int gc = cl ^ ((rl >> 1) & 3);
  const int rsw = (lc >> 1) & 3;
  const int nk = K / 32;

  auto stage = [&](int kt, int buf) {
    const int k0 = kt * 32;
    gld_lds16(&A[(size_t)(row0 + w * 16 + rl) * K + k0 + gc * 8],
              &As[buf * (TM * 32) + (w * 16) * 32]);
#pragma unroll
    for (int jb = 0; jb < TN / 64; ++jb)
      gld_lds16(&Bt[(size_t)(col0 + w * (TN / 4) + jb * 16 + rl) * K + k0 + gc * 8],
                &Bs[buf * (TN * 32) + (w * (TN / 4) + jb * 16) * 32]);
  };

  stage(0, 0);
  for (int kt = 0; kt < nk; ++kt) {
    const int bb = kt & 1;
    __syncthreads();
    if (kt + 1 < nk) stage(kt + 1, bb ^ 1);
    bf16x8 af[2], bfv[NT];
#pragma unroll
    for (int mt = 0; mt < 2; ++mt)
      af[mt] = *(const bf16x8*)&As[bb * (TM * 32) + (wm + mt * 16 + lc) * 32 + (quad ^ rsw) * 8];
#pragma unroll
    for (int nt = 0; nt < NT; ++nt)
      bfv[nt] = *(const bf16x8*)&Bs[bb * (TN * 32) + (wn + nt * 16 + lc) * 32 + (quad ^ rsw) * 8];
#pragma unroll
    for (int mt = 0; mt < 2; ++mt)
#pragma unroll
      for (int nt = 0; nt < NT; ++nt)
        acc[mt][nt] = __builtin_amdgcn_mfma_f32_16x16x32_bf16(af[mt], bfv[nt], acc[mt][nt], 0, 0, 0);
  }

  if (mode == 0 && col0 >= 1536) {
    __syncthreads();
#pragma unroll
    for (int mt = 0; mt < 2; ++mt) {
#pragma unroll
      for (int nt = 0; nt < NT; ++nt) {
        int jl = wn + nt * 16 + lc;
        int il0 = wm + mt * 16 + quad * 4;
        float bj = bias[col0 + jl];
        unsigned short a0 = f2bf(acc[mt][nt][0] + bj);
        unsigned short a1 = f2bf(acc[mt][nt][1] + bj);
        unsigned short a2 = f2bf(acc[mt][nt][2] + bj);
        unsigned short a3 = f2bf(acc[mt][nt][3] + bj);
        uint2 dd;
        dd.x = (unsigned)a0 | ((unsigned)a1 << 16);
        dd.y = (unsigned)a2 | ((unsigned)a3 << 16);
        *(uint2*)&Ct[jl * (TM + 8) + il0] = dd;
      }
    }
    __syncthreads();
    const int b = row0 >> 11, n0 = row0 & 2047;
    constexpr int CPR = TM / 8;
#pragma unroll
    for (int i = 0; i < (TN * CPR) / 256; ++i) {
      int c = tid + i * 256;
      int jl = c / CPR, cc = (c % CPR) * 8;
      u16x8 v = *(const u16x8*)&Ct[jl * (TM + 8) + cc];
      int jcol = col0 - 1536 + jl;
      int h = jcol >> 6, d = jcol & 63;
      size_t gr = ((size_t)(b * CH + h) * CDH + d);
      *(u16x8*)&o2[gr * CN + n0 + cc] = v;
    }
  } else {
#pragma unroll
    for (int mt = 0; mt < 2; ++mt) {
#pragma unroll
      for (int nt = 0; nt < NT; ++nt) {
#pragma unroll
        for (int r = 0; r < 4; ++r) {
          int i = row0 + wm + mt * 16 + quad * 4 + r;
          int j = col0 + wn + nt * 16 + lc;
          float v = acc[mt][nt][r] + bias[j];
          if (mode == 0) {
            int b = i >> 11, n = i & 2047;
            int sec = (j >= 768) ? 1 : 0;
            int within = j - sec * 768;
            int h = within >> 6, d = within & 63;
            int bh = b * CH + h;
            if (sec == 0) o0[((size_t)bh * CN + n) * CDH + d] = f2bf(v * CEXPSCALE);
            else          o1[((size_t)bh * CN + n) * CDH + d] = f2bf(v);
          } else {
            outF[(size_t)i * N + j] = v;
          }
        }
      }
    }
  }
}

// ---------------- flash attention, (q-half x key-half) wave split ------------
// grid (B*H, N/64). Block: 64 q-rows, 64-key tiles. Wave w: qh=w>>1, kh=w&1
// owns 32 q x 32 keys -> each K/V fragment read by 2 waves not 4
// (block-iter LDS 96->64 KB). Cross-kh O/l reduction via LDS overlay at end.
// Q arrives PRE-SCALED by log2(e)/8 -> p = exp2f(z) directly.
// KV layout (bf16 elems): K buf0 @0, K buf1 @4096, V buf0 @8192, V buf1 @12288.
__global__ __launch_bounds__(256, 3) void attn64(const unsigned short* __restrict__ Q,
                                                 const unsigned short* __restrict__ K,
                                                 const unsigned short* __restrict__ Vt,
                                                 unsigned short* __restrict__ O) {
  __shared__ __align__(16) unsigned short KV[4 * 4096];
  __shared__ __align__(16) unsigned short P[4][32 * 48];  // per-wave 32q x 32keys (stride 48)
  const int bh = blockIdx.x, qt = blockIdx.y;
  const int tid = threadIdx.x;
  const int w = tid >> 6, lane = tid & 63, quad = lane >> 4, lc = lane & 15;
  const int qh = w >> 1, kh = w & 1;
  const unsigned short* Qb = Q + (size_t)bh * CN * CDH;
  const unsigned short* Kb = K + (size_t)bh * CN * CDH;
  const unsigned short* Vb = Vt + (size_t)bh * CDH * CN;
  const int q0 = qt * 64 + qh * 32;

  const int sr = lane >> 3, sc = lane & 7;
  const int sg = sc ^ sr;             // staged global chunk for LDS chunk sc
  const int ksw = lc & 7;
  const int c0r = quad ^ ksw;         // LDS chunk holding global chunk quad
  const int c1r = c0r ^ 4;            // ... global chunk quad+4
  const int vcr = (kh * 4 + quad) ^ ksw;  // V: global chunk kh*4+quad

  bf16x8 qf[2][2];
#pragma unroll
  for (int s = 0; s < 2; ++s) {
    qf[s][0] = *(const bf16x8*)&Qb[(size_t)(q0 + s * 16 + lc) * CDH + quad * 8];
    qf[s][1] = *(const bf16x8*)&Qb[(size_t)(q0 + s * 16 + lc) * CDH + 32 + quad * 8];
  }

  f32x4 o[2][4] = {};
  float rs[2] = {0.f, 0.f};

  // prologue: stage tile 0 (wave w stages rows [16w,16w+16) of K and V)
#pragma unroll
  for (int j2 = 0; j2 < 2; ++j2) {
    int j = w * 2 + j2;
    int r = j * 8 + sr;
    gld_lds16(&Kb[(size_t)r * CDH + sg * 8], &KV[j * 8 * 64]);
    gld_lds16(&Vb[(size_t)r * CN + 0 + sg * 8], &KV[8192 + j * 8 * 64]);
  }

  for (int kt = 0; kt < CN / 64; ++kt) {
    const int bb = kt & 1;
    const int kbase = bb * 4096;
    const int vbase = 8192 + bb * 4096;
    __syncthreads();  // tile kt staged
    if (kt + 1 < CN / 64) {
      const int kn = (kt + 1) * 64;
      const int kbn = (bb ^ 1) * 4096;
      const int vbn = 8192 + (bb ^ 1) * 4096;
#pragma unroll
      for (int j2 = 0; j2 < 2; ++j2) {
        int j = w * 2 + j2;
        int r = j * 8 + sr;
        gld_lds16(&Kb[(size_t)(kn + r) * CDH + sg * 8], &KV[kbn + j * 8 * 64]);
        gld_lds16(&Vb[(size_t)r * CN + kn + sg * 8], &KV[vbn + j * 8 * 64]);
      }
    }
    // ---- S^T for my 32 keys x 32 q: lane holds [key=ks*16+quad*4+r][q=s*16+lc]
#pragma unroll
    for (int ks = 0; ks < 2; ++ks) {
      const int krow = kh * 32 + ks * 16 + lc;
      bf16x8 kf0 = *(const bf16x8*)&KV[kbase + krow * 64 + c0r * 8];
      bf16x8 kf1 = *(const bf16x8*)&KV[kbase + krow * 64 + c1r * 8];
#pragma unroll
      for (int s = 0; s < 2; ++s) {
        f32x4 z = {0.f, 0.f, 0.f, 0.f};
        z = __builtin_amdgcn_mfma_f32_16x16x32_bf16(kf0, qf[s][0], z, 0, 0, 0);
        z = __builtin_amdgcn_mfma_f32_16x16x32_bf16(kf1, qf[s][1], z, 0, 0, 0);
        float p0 = exp2f(z[0]);
        float p1 = exp2f(z[1]);
        float p2 = exp2f(z[2]);
        float p3 = exp2f(z[3]);
        rs[s] += (p0 + p1) + (p2 + p3);
        unsigned d0 = __builtin_amdgcn_perm(__float_as_uint(p1), __float_as_uint(p0), 0x07060302u);
        unsigned d1 = __builtin_amdgcn_perm(__float_as_uint(p3), __float_as_uint(p2), 0x07060302u);
        uint2 dd; dd.x = d0; dd.y = d1;
        *(uint2*)&P[w][(s * 16 + lc) * 48 + ks * 16 + quad * 4] = dd;
      }
    }
    // order ds_write -> ds_read within the wave (vmcnt untouched)
    asm volatile("s_waitcnt lgkmcnt(0)" ::: "memory");
    bf16x8 pf[2];
#pragma unroll
    for (int s = 0; s < 2; ++s)
      pf[s] = *(const bf16x8*)&P[w][(s * 16 + lc) * 48 + quad * 8];
    // ---- O += P V over my 32 keys (K=32 single MFMA per (s,dt)) ----
#pragma unroll
    for (int dt = 0; dt < 4; ++dt) {
      bf16x8 vf = *(const bf16x8*)&KV[vbase + (dt * 16 + lc) * 64 + vcr * 8];
#pragma unroll
      for (int s = 0; s < 2; ++s)
        o[s][dt] = __builtin_amdgcn_mfma_f32_16x16x32_bf16(pf[s], vf, o[s][dt], 0, 0, 0);
    }
  }

  // ---- reduce rs over quads (each lane ends with row-sum for q=s*16+lc) ----
#pragma unroll
  for (int s = 0; s < 2; ++s) {
    rs[s] += __shfl_xor(rs[s], 16, 64);
    rs[s] += __shfl_xor(rs[s], 32, 64);
  }

  // ---- cross-keyhalf reduction via LDS overlay on KV ----
  // ex: [qh][d 64][q 36 stride] fp32 (18.4 KB); rs_lds after it.
  float* ex = (float*)KV;
  float* rs_lds = (float*)((char*)KV + 2 * 64 * 36 * 4);
  __syncthreads();  // all compute reads of KV done
  if (kh == 1) {
#pragma unroll
    for (int dt = 0; dt < 4; ++dt)
#pragma unroll
      for (int s = 0; s < 2; ++s)
        *(f32x4*)&ex[(qh * 64 + dt * 16 + lc) * 36 + s * 16 + quad * 4] = o[s][dt];
    if (quad == 0) {
      rs_lds[qh * 32 + lc] = rs[0];
      rs_lds[qh * 32 + 16 + lc] = rs[1];
    }
  }
  __syncthreads();
  if (kh == 0) {
    const int b = bh / CH, h = bh - b * CH;
#pragma unroll
    for (int s = 0; s < 2; ++s) {
      float lt = rs[s] + rs_lds[qh * 32 + s * 16 + lc];  // total l for q=s*16+lc
#pragma unroll
      for (int r = 0; r < 4; ++r) {
        float lr = __shfl(lt, quad * 4 + r, 64);
        float inv = 1.0f / lr;
#pragma unroll
        for (int dt = 0; dt < 4; ++dt) {
          f32x4 part = *(const f32x4*)&ex[(qh * 64 + dt * 16 + lc) * 36 + s * 16 + quad * 4];
          int i = b * CN + q0 + s * 16 + quad * 4 + r;
          int j = h * CDH + dt * 16 + lc;
          O[(size_t)i * CD + j] = f2bf((o[s][dt][r] + part[r]) * inv);
        }
      }
    }
  }
}

extern "C" void kernel_launch(void* const* d_in, const int* in_sizes, int n_in,
                              void* d_out, int out_size, void* d_ws, size_t ws_size,
                              hipStream_t stream) {
  const float* x      = (const float*)d_in[0];
  const float* w_qkv  = (const float*)d_in[1];
  const float* b_qkv  = (const float*)d_in[2];
  const float* w_proj = (const float*)d_in[3];
  const float* b_proj = (const float*)d_in[4];
  float* out = (float*)d_out;
  unsigned short* ws = (unsigned short*)d_ws;

  unsigned short* xb      = ws;
  unsigned short* wqkv_t  = xb + (size_t)4096 * 768;
  unsigned short* wproj_t = wqkv_t + (size_t)2304 * 768;
  unsigned short* Qs  = wproj_t + (size_t)768 * 768;
  unsigned short* Ks  = Qs  + (size_t)CB * CH * CN * CDH;
  unsigned short* Vts = Ks  + (size_t)CB * CH * CN * CDH;
  unsigned short* AO  = Vts + (size_t)CB * CH * CN * CDH;

  const size_t smem_qkv  = (size_t)2 * (64 + 128) * 32 * 2;  // 24576 B
  const size_t smem_proj = (size_t)2 * (64 + 64) * 32 * 2;   // 16384 B

  prep<<<768, 256, 0, stream>>>(x, xb, w_qkv, wqkv_t, w_proj, wproj_t);
  gemm_db<64, 128><<<dim3(2304 / 128, 4096 / 64), 256, smem_qkv, stream>>>(
      xb, wqkv_t, b_qkv, 4096, 2304, 768, 0, Qs, Ks, Vts, nullptr);
  attn64<<<dim3(CB * CH, CN / 64), 256, 0, stream>>>(Qs, Ks, Vts, AO);
  gemm_db<64, 64><<<dim3(768 / 64, 4096 / 64), 256, smem_proj, stream>>>(
      AO, wproj_t, b_proj, 4096, 768, 768, 1, nullptr, nullptr, nullptr, out);
}

// Round 12
// 170.723 us; speedup vs baseline: 1.0393x; 1.0393x over previous
//
#include <hip/hip_runtime.h>

// MultiHeadSelfAttention: B=2, N=2048, D=768, H=12, DH=64, scale=1/8.
// d_in / d_out are FP32; grading is bf16-leniency (2% of absmax).
// R12: (a) attn P stride 48->56 elems (48 = 24 dwords, gcd(24,32)=8 -> 4-way
//      bank conflicts; 56 = 28 dwords -> 2-way = free; R11's +2.44M conflicts
//      == the 5.4us regression). (b) QKV Q/K epilogue through LDS like V:
//      b16 scatter -> Ct[il][jl] (stride 140, conflict-clean) -> b128
//      coalesced global stores (was 32 scalar 2-B stores/lane).

#define CB 2
#define CN 2048
#define CD 768
#define CH 12
#define CDH 64
// exp(s/8) = exp2(s * 0.125 * log2(e)) ; folded into Q at QKV epilogue
#define CEXPSCALE 0.18033688f

typedef __bf16 bf16x8 __attribute__((ext_vector_type(8)));
typedef float f32x4 __attribute__((ext_vector_type(4)));
typedef unsigned short u16x8 __attribute__((ext_vector_type(8)));

static __device__ __forceinline__ unsigned short f2bf(float f) {
  union { float f; unsigned u; } v; v.f = f;
  unsigned r = v.u + 0x7fffu + ((v.u >> 16) & 1u);  // RNE
  return (unsigned short)(r >> 16);
}

// async global->LDS, 16B per lane; LDS dest = wave-uniform base + lane*16
static __device__ __forceinline__ void gld_lds16(const unsigned short* g, unsigned short* lds_base) {
  __builtin_amdgcn_global_load_lds(
      (const __attribute__((address_space(1))) unsigned int*)g,
      (__attribute__((address_space(3))) unsigned int*)(unsigned int)(unsigned long long)lds_base,
      16, 0, 0);
}

// ---------------- fused prep: cvt x -> bf16 AND transpose+cvt both weights ----
__global__ __launch_bounds__(256) void prep(const float* __restrict__ x,
                                            unsigned short* __restrict__ xb,
                                            const float* __restrict__ w_qkv,
                                            unsigned short* __restrict__ wqkv_t,
                                            const float* __restrict__ w_proj,
                                            unsigned short* __restrict__ wproj_t) {
  __shared__ __align__(16) unsigned short t[64][72];
  const int bid = blockIdx.x, tid = threadIdx.x;
#pragma unroll
  for (int it = 0; it < 2; ++it) {
    size_t i = ((size_t)(bid * 2 + it) * 256 + tid) * 8;
    f32x4 a = *(const f32x4*)&x[i];
    f32x4 b = *(const f32x4*)&x[i + 4];
    u16x8 o;
#pragma unroll
    for (int j = 0; j < 4; ++j) { o[j] = f2bf(a[j]); o[4 + j] = f2bf(b[j]); }
    *(u16x8*)&xb[i] = o;
  }
  if (bid >= 576) return;
  const float* src; unsigned short* dst; int R, C, c0, r0;
  if (bid < 432) { src = w_qkv; dst = wqkv_t; R = 768; C = 2304; c0 = (bid % 36) * 64; r0 = (bid / 36) * 64; }
  else { int u = bid - 432; src = w_proj; dst = wproj_t; R = 768; C = 768; c0 = (u % 12) * 64; r0 = (u / 12) * 64; }
#pragma unroll
  for (int i = 0; i < 4; ++i) {
    int c = tid + i * 256;
    int row = c >> 4, cc = (c & 15) * 4;
    f32x4 v = *(const f32x4*)&src[(size_t)(r0 + row) * C + c0 + cc];
#pragma unroll
    for (int j = 0; j < 4; ++j) t[row][cc + j] = f2bf(v[j]);
  }
  __syncthreads();
#pragma unroll
  for (int i = 0; i < 2; ++i) {
    int c = tid + i * 256;
    int drow = c >> 3, rc = (c & 7) * 8;
    u16x8 v;
#pragma unroll
    for (int j = 0; j < 8; ++j) v[j] = t[rc + j][drow];
    *(u16x8*)&dst[(size_t)(c0 + drow) * R + r0 + rc] = v;
  }
}

// ---------------- GEMM, double-buffered ----------------
// mode 0 (QKV): V blocks (col0>=1536) -> transposed via Ct, b128 stores;
//               Q/K blocks -> Ct [il][jl] stride 140, b128 coalesced stores
//               (Q pre-scaled by CEXPSCALE). mode 1: fp32 row-major.
extern __shared__ __align__(16) unsigned short smem[];

template <int TM, int TN>
__global__ __launch_bounds__(256, 4) void gemm_db(const unsigned short* __restrict__ A,
                                                  const unsigned short* __restrict__ Bt,
                                                  const float* __restrict__ bias,
                                                  int M, int N, int K, int mode,
                                                  unsigned short* __restrict__ o0,
                                                  unsigned short* __restrict__ o1,
                                                  unsigned short* __restrict__ o2,
                                                  float* __restrict__ outF) {
  constexpr int NT = TN / 32;
  unsigned short* As = smem;
  unsigned short* Bs = smem + 2 * TM * 32;
  unsigned short* Ct = smem;
  const int tid = threadIdx.x;
  const int w = tid >> 6, lane = tid & 63, quad = lane >> 4, lc = lane & 15;
  const int wm = (w >> 1) * 32, wn = (w & 1) * (TN / 2);
  const int row0 = blockIdx.y * TM, col0 = blockIdx.x * TN;
  f32x4 acc[2][NT] = {};

  const int rl = lane >> 2, cl = lane & 3;
  const int gc = cl ^ ((rl >> 1) & 3);
  const int rsw = (lc >> 1) & 3;
  const int nk = K / 32;

  auto stage = [&](int kt, int buf) {
    const int k0 = kt * 32;
    gld_lds16(&A[(size_t)(row0 + w * 16 + rl) * K + k0 + gc * 8],
              &As[buf * (TM * 32) + (w * 16) * 32]);
#pragma unroll
    for (int jb = 0; jb < TN / 64; ++jb)
      gld_lds16(&Bt[(size_t)(col0 + w * (TN / 4) + jb * 16 + rl) * K + k0 + gc * 8],
                &Bs[buf * (TN * 32) + (w * (TN / 4) + jb * 16) * 32]);
  };

  stage(0, 0);
  for (int kt = 0; kt < nk; ++kt) {
    const int bb = kt & 1;
    __syncthreads();
    if (kt + 1 < nk) stage(kt + 1, bb ^ 1);
    bf16x8 af[2], bfv[NT];
#pragma unroll
    for (int mt = 0; mt < 2; ++mt)
      af[mt] = *(const bf16x8*)&As[bb * (TM * 32) + (wm + mt * 16 + lc) * 32 + (quad ^ rsw) * 8];
#pragma unroll
    for (int nt = 0; nt < NT; ++nt)
      bfv[nt] = *(const bf16x8*)&Bs[bb * (TN * 32) + (wn + nt * 16 + lc) * 32 + (quad ^ rsw) * 8];
#pragma unroll
    for (int mt = 0; mt < 2; ++mt)
#pragma unroll
      for (int nt = 0; nt < NT; ++nt)
        acc[mt][nt] = __builtin_amdgcn_mfma_f32_16x16x32_bf16(af[mt], bfv[nt], acc[mt][nt], 0, 0, 0);
  }

  if (mode == 0) {
    __syncthreads();  // all frag reads of As/Bs done; Ct overlay safe
    if (col0 >= 1536) {
      // -------- V block: transpose through LDS, store V^T coalesced --------
#pragma unroll
      for (int mt = 0; mt < 2; ++mt) {
#pragma unroll
        for (int nt = 0; nt < NT; ++nt) {
          int jl = wn + nt * 16 + lc;
          int il0 = wm + mt * 16 + quad * 4;
          float bj = bias[col0 + jl];
          unsigned short a0 = f2bf(acc[mt][nt][0] + bj);
          unsigned short a1 = f2bf(acc[mt][nt][1] + bj);
          unsigned short a2 = f2bf(acc[mt][nt][2] + bj);
          unsigned short a3 = f2bf(acc[mt][nt][3] + bj);
          uint2 dd;
          dd.x = (unsigned)a0 | ((unsigned)a1 << 16);
          dd.y = (unsigned)a2 | ((unsigned)a3 << 16);
          *(uint2*)&Ct[jl * (TM + 8) + il0] = dd;
        }
      }
      __syncthreads();
      const int b = row0 >> 11, n0 = row0 & 2047;
      constexpr int CPR = TM / 8;
#pragma unroll
      for (int i = 0; i < (TN * CPR) / 256; ++i) {
        int c = tid + i * 256;
        int jl = c / CPR, cc = (c % CPR) * 8;
        u16x8 v = *(const u16x8*)&Ct[jl * (TM + 8) + cc];
        int jcol = col0 - 1536 + jl;
        int h = jcol >> 6, d = jcol & 63;
        size_t gr = ((size_t)(b * CH + h) * CDH + d);
        *(u16x8*)&o2[gr * CN + n0 + cc] = v;
      }
    } else {
      // -------- Q/K block: LDS re-stage -> b128 coalesced [n][d] stores -----
      const float sc = (col0 < 768) ? CEXPSCALE : 1.0f;
#pragma unroll
      for (int mt = 0; mt < 2; ++mt) {
#pragma unroll
        for (int nt = 0; nt < NT; ++nt) {
          int jl = wn + nt * 16 + lc;
          float bj = bias[col0 + jl];
#pragma unroll
          for (int r = 0; r < 4; ++r) {
            int il = wm + mt * 16 + quad * 4 + r;
            Ct[il * 140 + jl] = f2bf((acc[mt][nt][r] + bj) * sc);
          }
        }
      }
      __syncthreads();
      const int b = row0 >> 11, n0 = row0 & 2047;
      unsigned short* dst = (col0 < 768) ? o0 : o1;
      const int hbase = ((col0 < 768) ? col0 : col0 - 768) >> 6;
      constexpr int QKIT = (TM * TN / 8) / 256;
#pragma unroll
      for (int i = 0; i < QKIT; ++i) {
        int c = tid + i * 256;                 // TM rows x TN/8 chunks
        int il = c / (TN / 8), cc = (c % (TN / 8)) * 8;
        u16x8 v = *(const u16x8*)&Ct[il * 140 + cc];
        int h = hbase + (cc >> 6), d = cc & 63;
        *(u16x8*)&dst[(((size_t)(b * CH + h) * CN) + n0 + il) * CDH + d] = v;
      }
    }
  } else {
#pragma unroll
    for (int mt = 0; mt < 2; ++mt) {
#pragma unroll
      for (int nt = 0; nt < NT; ++nt) {
#pragma unroll
        for (int r = 0; r < 4; ++r) {
          int i = row0 + wm + mt * 16 + quad * 4 + r;
          int j = col0 + wn + nt * 16 + lc;
          outF[(size_t)i * N + j] = acc[mt][nt][r] + bias[j];
        }
      }
    }
  }
}

// ---------------- flash attention, (q-half x key-half) wave split ------------
// grid (B*H, N/64). Wave w: qh=w>>1, kh=w&1 owns 32 q x 32 keys.
// P stride 56 elems (28 dwords -> 2-way-only bank aliasing; 48 was 4-way).
// Q arrives PRE-SCALED by log2(e)/8 -> p = exp2f(z) directly.
// KV layout (bf16 elems): K buf0 @0, K buf1 @4096, V buf0 @8192, V buf1 @12288.
__global__ __launch_bounds__(256, 3) void attn64(const unsigned short* __restrict__ Q,
                                                 const unsigned short* __restrict__ K,
                                                 const unsigned short* __restrict__ Vt,
                                                 unsigned short* __restrict__ O) {
  __shared__ __align__(16) unsigned short KV[4 * 4096];
  __shared__ __align__(16) unsigned short P[4][32 * 56];  // per-wave 32q x 32keys (stride 56)
  const int bh = blockIdx.x, qt = blockIdx.y;
  const int tid = threadIdx.x;
  const int w = tid >> 6, lane = tid & 63, quad = lane >> 4, lc = lane & 15;
  const int qh = w >> 1, kh = w & 1;
  const unsigned short* Qb = Q + (size_t)bh * CN * CDH;
  const unsigned short* Kb = K + (size_t)bh * CN * CDH;
  const unsigned short* Vb = Vt + (size_t)bh * CDH * CN;
  const int q0 = qt * 64 + qh * 32;

  const int sr = lane >> 3, sc = lane & 7;
  const int sg = sc ^ sr;             // staged global chunk for LDS chunk sc
  const int ksw = lc & 7;
  const int c0r = quad ^ ksw;         // LDS chunk holding global chunk quad
  const int c1r = c0r ^ 4;            // ... global chunk quad+4
  const int vcr = (kh * 4 + quad) ^ ksw;  // V: global chunk kh*4+quad

  bf16x8 qf[2][2];
#pragma unroll
  for (int s = 0; s < 2; ++s) {
    qf[s][0] = *(const bf16x8*)&Qb[(size_t)(q0 + s * 16 + lc) * CDH + quad * 8];
    qf[s][1] = *(const bf16x8*)&Qb[(size_t)(q0 + s * 16 + lc) * CDH + 32 + quad * 8];
  }

  f32x4 o[2][4] = {};
  float rs[2] = {0.f, 0.f};

  // prologue: stage tile 0 (wave w stages rows [16w,16w+16) of K and V)
#pragma unroll
  for (int j2 = 0; j2 < 2; ++j2) {
    int j = w * 2 + j2;
    int r = j * 8 + sr;
    gld_lds16(&Kb[(size_t)r * CDH + sg * 8], &KV[j * 8 * 64]);
    gld_lds16(&Vb[(size_t)r * CN + 0 + sg * 8], &KV[8192 + j * 8 * 64]);
  }

  for (int kt = 0; kt < CN / 64; ++kt) {
    const int bb = kt & 1;
    const int kbase = bb * 4096;
    const int vbase = 8192 + bb * 4096;
    __syncthreads();  // tile kt staged
    if (kt + 1 < CN / 64) {
      const int kn = (kt + 1) * 64;
      const int kbn = (bb ^ 1) * 4096;
      const int vbn = 8192 + (bb ^ 1) * 4096;
#pragma unroll
      for (int j2 = 0; j2 < 2; ++j2) {
        int j = w * 2 + j2;
        int r = j * 8 + sr;
        gld_lds16(&Kb[(size_t)(kn + r) * CDH + sg * 8], &KV[kbn + j * 8 * 64]);
        gld_lds16(&Vb[(size_t)r * CN + kn + sg * 8], &KV[vbn + j * 8 * 64]);
      }
    }
    // ---- S^T for my 32 keys x 32 q: lane holds [key=ks*16+quad*4+r][q=s*16+lc]
#pragma unroll
    for (int ks = 0; ks < 2; ++ks) {
      const int krow = kh * 32 + ks * 16 + lc;
      bf16x8 kf0 = *(const bf16x8*)&KV[kbase + krow * 64 + c0r * 8];
      bf16x8 kf1 = *(const bf16x8*)&KV[kbase + krow * 64 + c1r * 8];
#pragma unroll
      for (int s = 0; s < 2; ++s) {
        f32x4 z = {0.f, 0.f, 0.f, 0.f};
        z = __builtin_amdgcn_mfma_f32_16x16x32_bf16(kf0, qf[s][0], z, 0, 0, 0);
        z = __builtin_amdgcn_mfma_f32_16x16x32_bf16(kf1, qf[s][1], z, 0, 0, 0);
        float p0 = exp2f(z[0]);
        float p1 = exp2f(z[1]);
        float p2 = exp2f(z[2]);
        float p3 = exp2f(z[3]);
        rs[s] += (p0 + p1) + (p2 + p3);
        unsigned d0 = __builtin_amdgcn_perm(__float_as_uint(p1), __float_as_uint(p0), 0x07060302u);
        unsigned d1 = __builtin_amdgcn_perm(__float_as_uint(p3), __float_as_uint(p2), 0x07060302u);
        uint2 dd; dd.x = d0; dd.y = d1;
        *(uint2*)&P[w][(s * 16 + lc) * 56 + ks * 16 + quad * 4] = dd;
      }
    }
    // order ds_write -> ds_read within the wave (vmcnt untouched)
    asm volatile("s_waitcnt lgkmcnt(0)" ::: "memory");
    bf16x8 pf[2];
#pragma unroll
    for (int s = 0; s < 2; ++s)
      pf[s] = *(const bf16x8*)&P[w][(s * 16 + lc) * 56 + quad * 8];
    // ---- O += P V over my 32 keys (K=32 single MFMA per (s,dt)) ----
#pragma unroll
    for (int dt = 0; dt < 4; ++dt) {
      bf16x8 vf = *(const bf16x8*)&KV[vbase + (dt * 16 + lc) * 64 + vcr * 8];
#pragma unroll
      for (int s = 0; s < 2; ++s)
        o[s][dt] = __builtin_amdgcn_mfma_f32_16x16x32_bf16(pf[s], vf, o[s][dt], 0, 0, 0);
    }
  }

  // ---- reduce rs over quads (each lane ends with row-sum for q=s*16+lc) ----
#pragma unroll
  for (int s = 0; s < 2; ++s) {
    rs[s] += __shfl_xor(rs[s], 16, 64);
    rs[s] += __shfl_xor(rs[s], 32, 64);
  }

  // ---- cross-keyhalf reduction via LDS overlay on KV ----
  float* ex = (float*)KV;
  float* rs_lds = (float*)((char*)KV + 2 * 64 * 36 * 4);
  __syncthreads();  // all compute reads of KV done
  if (kh == 1) {
#pragma unroll
    for (int dt = 0; dt < 4; ++dt)
#pragma unroll
      for (int s = 0; s < 2; ++s)
        *(f32x4*)&ex[(qh * 64 + dt * 16 + lc) * 36 + s * 16 + quad * 4] = o[s][dt];
    if (quad == 0) {
      rs_lds[qh * 32 + lc] = rs[0];
      rs_lds[qh * 32 + 16 + lc] = rs[1];
    }
  }
  __syncthreads();
  if (kh == 0) {
    const int b = bh / CH, h = bh - b * CH;
#pragma unroll
    for (int s = 0; s < 2; ++s) {
      float lt = rs[s] + rs_lds[qh * 32 + s * 16 + lc];
#pragma unroll
      for (int r = 0; r < 4; ++r) {
        float lr = __shfl(lt, quad * 4 + r, 64);
        float inv = 1.0f / lr;
#pragma unroll
        for (int dt = 0; dt < 4; ++dt) {
          f32x4 part = *(const f32x4*)&ex[(qh * 64 + dt * 16 + lc) * 36 + s * 16 + quad * 4];
          int i = b * CN + q0 + s * 16 + quad * 4 + r;
          int j = h * CDH + dt * 16 + lc;
          O[(size_t)i * CD + j] = f2bf((o[s][dt][r] + part[r]) * inv);
        }
      }
    }
  }
}

extern "C" void kernel_launch(void* const* d_in, const int* in_sizes, int n_in,
                              void* d_out, int out_size, void* d_ws, size_t ws_size,
                              hipStream_t stream) {
  const float* x      = (const float*)d_in[0];
  const float* w_qkv  = (const float*)d_in[1];
  const float* b_qkv  = (const float*)d_in[2];
  const float* w_proj = (const float*)d_in[3];
  const float* b_proj = (const float*)d_in[4];
  float* out = (float*)d_out;
  unsigned short* ws = (unsigned short*)d_ws;

  unsigned short* xb      = ws;
  unsigned short* wqkv_t  = xb + (size_t)4096 * 768;
  unsigned short* wproj_t = wqkv_t + (size_t)2304 * 768;
  unsigned short* Qs  = wproj_t + (size_t)768 * 768;
  unsigned short* Ks  = Qs  + (size_t)CB * CH * CN * CDH;
  unsigned short* Vts = Ks  + (size_t)CB * CH * CN * CDH;
  unsigned short* AO  = Vts + (size_t)CB * CH * CN * CDH;

  const size_t smem_qkv  = (size_t)2 * (64 + 128) * 32 * 2;  // 24576 B (Ct overlays)
  const size_t smem_proj = (size_t)2 * (64 + 64) * 32 * 2;   // 16384 B

  prep<<<768, 256, 0, stream>>>(x, xb, w_qkv, wqkv_t, w_proj, wproj_t);
  gemm_db<64, 128><<<dim3(2304 / 128, 4096 / 64), 256, smem_qkv, stream>>>(
      xb, wqkv_t, b_qkv, 4096, 2304, 768, 0, Qs, Ks, Vts, nullptr);
  attn64<<<dim3(CB * CH, CN / 64), 256, 0, stream>>>(Qs, Ks, Vts, AO);
  gemm_db<64, 64><<<dim3(768 / 64, 4096 / 64), 256, smem_proj, stream>>>(
      AO, wproj_t, b_proj, 4096, 768, 768, 1, nullptr, nullptr, nullptr, out);
}